// Round 19
// baseline (144.967 us; speedup 1.0000x reference)
//
#include <hip/hip_runtime.h>
#include <hip/hip_bf16.h>
#include <stdint.h>

#define HEADS 12
#define HD 64
#define SEQ 1024
#define CDIM 768
#define LOG2E 1.44269504f

typedef __attribute__((ext_vector_type(8))) short bfrag;     // 8 bf16 (4 VGPRs)
typedef __attribute__((ext_vector_type(4))) float facc;      // 4 fp32 accum
typedef __attribute__((ext_vector_type(4))) _Float16 h4;     // 4 fp16 (2 VGPRs)
typedef __attribute__((ext_vector_type(2))) __fp16 pk2;      // cvt_pkrtz result type

__device__ __forceinline__ ushort f2bf(float f) {
    union { float f; uint32_t u; } v; v.f = f;
    uint32_t u = v.u;
    uint32_t r = (u + 0x7FFFu + ((u >> 16) & 1u)) >> 16;
    return (ushort)r;
}
__device__ __forceinline__ ushort f2h(float f) {
    union { _Float16 h; ushort u; } c; c.h = (_Float16)f; return c.u;
}
__device__ __forceinline__ float h2f(uint32_t u16) {
    union { _Float16 h; ushort u; } c; c.u = (ushort)u16; return (float)c.h;
}
__device__ __forceinline__ h4 pack4h(float p0, float p1, float p2, float p3) {
    union { h4 v4; pk2 v2[2]; } u;
    u.v2[0] = __builtin_amdgcn_cvt_pkrtz(p0, p1);
    u.v2[1] = __builtin_amdgcn_cvt_pkrtz(p2, p3);
    return u.v4;
}
// bare v_exp_f32 (2^x) — avoids libm exp2 range-fixup expansion
__device__ __forceinline__ float exp2_raw(float x) {
    float r;
    asm("v_exp_f32 %0, %1" : "=v"(r) : "v"(x));
    return r;
}

// ---------------- fused fp32 -> bf16 converts (x, qkv_w, proj_w) ----------------
__global__ void cvt_all(const float* __restrict__ x, const float* __restrict__ qw,
                        const float* __restrict__ pw,
                        ushort* __restrict__ xd, ushort* __restrict__ qd,
                        ushort* __restrict__ pd) {
    long i = ((long)blockIdx.x * 256 + threadIdx.x) * 4;
    if (i < 6291456) {
        float4 v = *(const float4*)(x + i);
        ushort4 o = {f2bf(v.x), f2bf(v.y), f2bf(v.z), f2bf(v.w)};
        *(ushort4*)(xd + i) = o;
    } else if (i < 8060928) {
        long j = i - 6291456;
        float4 v = *(const float4*)(qw + j);
        ushort4 o = {f2bf(v.x), f2bf(v.y), f2bf(v.z), f2bf(v.w)};
        *(ushort4*)(qd + j) = o;
    } else if (i < 8650752) {
        long j = i - 8060928;
        float4 v = *(const float4*)(pw + j);
        ushort4 o = {f2bf(v.x), f2bf(v.y), f2bf(v.z), f2bf(v.w)};
        *(ushort4*)(pd + j) = o;
    }
}

#define GLOAD16(gsrc, ldst) \
    __builtin_amdgcn_global_load_lds((const __attribute__((address_space(1))) uint32_t*)(gsrc), \
                                     (__attribute__((address_space(3))) uint32_t*)(ldst), 16, 0, 0)

// ---------------- NT GEMM, 128x128 tile, BK=64, swizzled DMA staging [r18, frozen] ----------------
template<int EPI>
__global__ __launch_bounds__(256) void gemm_nt(
    const ushort* __restrict__ A, const ushort* __restrict__ Bm,
    ushort* __restrict__ qb, ushort* __restrict__ kb, ushort* __restrict__ vb,
    const float* __restrict__ projb, float* __restrict__ out,
    const float* __restrict__ relf, ushort* __restrict__ biash)
{
    __shared__ ushort As[128 * 64];
    __shared__ ushort Bs[128 * 64];
    const int t = threadIdx.x;

    int m0, o0;
    if (EPI == 0) {
        if (blockIdx.y < 4) {
            const int cb = blockIdx.y * 64 + blockIdx.x;    // 0..255
#pragma unroll 4
            for (int s = 0; s < 48; ++s) {
                long i = (((long)s * 256 + cb) * 256 + t) * 4;
                float4 v = *(const float4*)(relf + i);
                ushort4 o = {f2h(v.x * LOG2E), f2h(v.y * LOG2E),
                             f2h(v.z * LOG2E), f2h(v.w * LOG2E)};
                *(ushort4*)(biash + i) = o;
            }
            return;
        }
        m0 = blockIdx.x * 128;
        o0 = (blockIdx.y - 4) * 128;
    } else {
        m0 = blockIdx.x * 128;
        o0 = blockIdx.y * 128;
    }

    const int w = t >> 6, l = t & 63;
    const int wm = w >> 1, wn = w & 1;
    const int lr = l & 15, lg = l >> 4;

    facc acc[4][4] = {};

    const int srow = w * 8 + (l >> 3);
    const int sgr  = ((l & 7) ^ (l >> 3)) * 8;
    const ushort* Ag = A + (size_t)(m0 + srow) * CDIM + sgr;
    const ushort* Bg = Bm + (size_t)(o0 + srow) * CDIM + sgr;
    const int ldst = w * 512 + l * 8;                 // + j*2048

    for (int k0 = 0; k0 < CDIM; k0 += 64) {
        __syncthreads();
#pragma unroll
        for (int j = 0; j < 4; ++j) {
            GLOAD16(Ag + (size_t)(j * 32) * CDIM + k0, As + j * 2048 + ldst);
            GLOAD16(Bg + (size_t)(j * 32) * CDIM + k0, Bs + j * 2048 + ldst);
        }
        __syncthreads();
#pragma unroll
        for (int s = 0; s < 2; ++s) {
            bfrag af[4], bf[4];
            const int rg = ((s * 4 + lg) ^ (lr & 7)) * 8;   // swizzled read granule
#pragma unroll
            for (int m = 0; m < 4; ++m)
                af[m] = *(const bfrag*)&As[(wm * 64 + m * 16 + lr) * 64 + rg];
#pragma unroll
            for (int n = 0; n < 4; ++n)
                bf[n] = *(const bfrag*)&Bs[(wn * 64 + n * 16 + lr) * 64 + rg];
#pragma unroll
            for (int m = 0; m < 4; ++m)
#pragma unroll
                for (int n = 0; n < 4; ++n)
                    acc[m][n] = __builtin_amdgcn_mfma_f32_16x16x32_bf16(af[m], bf[n], acc[m][n], 0, 0, 0);
        }
    }

    if (EPI == 0) {
        const int tsel = o0 / CDIM;
        const int h_base = (o0 % CDIM) / 64;
        if (tsel == 2) {
            // V TRANSPOSED: vb[bh][d][seq] fp16, vectorized over 4 consecutive seq (r)
#pragma unroll
            for (int m = 0; m < 4; ++m) {
                int grow = m0 + wm * 64 + m * 16 + lg * 4;
                int b = grow >> 10, nn = grow & 1023;
#pragma unroll
                for (int n = 0; n < 4; ++n) {
                    int h = h_base + wn;
                    int d = n * 16 + lr;
                    ushort4 pk = {f2h(acc[m][n][0]), f2h(acc[m][n][1]),
                                  f2h(acc[m][n][2]), f2h(acc[m][n][3])};
                    *(ushort4*)&vb[(((size_t)(b * HEADS + h)) * 64 + d) * 1024 + nn] = pk;
                }
            }
        } else {
            ushort* dst = (tsel == 0) ? qb : kb;
            const float scl = (tsel == 0) ? 0.18033688f : 1.0f;   // 0.125 * log2(e)
#pragma unroll
            for (int m = 0; m < 4; ++m) {
                int grow = m0 + wm * 64 + m * 16 + lg * 4;
#pragma unroll
                for (int n = 0; n < 4; ++n) {
                    int h = h_base + wn;
                    int d = n * 16 + lr;
#pragma unroll
                    for (int r = 0; r < 4; ++r) {
                        int row = grow + r;
                        int b = row >> 10, nn = row & 1023;
                        dst[(((size_t)(b * HEADS + h)) * SEQ + nn) * HD + d] = f2bf(acc[m][n][r] * scl);
                    }
                }
            }
        }
    } else {
#pragma unroll
        for (int m = 0; m < 4; ++m) {
            int grow = m0 + wm * 64 + m * 16 + lg * 4;
#pragma unroll
            for (int n = 0; n < 4; ++n) {
                int o = o0 + wn * 64 + n * 16 + lr;
                float bias = projb[o];
#pragma unroll
                for (int r = 0; r < 4; ++r)
                    out[(size_t)(grow + r) * CDIM + o] = acc[m][n][r] + bias;
            }
        }
    }
}

// ---------------- fused flash attention: QBLK=64, DMA-staged K/V^T, XOR swizzle ----------------
// grid: 1536 (XCD-swizzled, 192 lids/XCD). Block = 64 q rows; 4 waves x 16 q rows each.
// DMA staging identical per block (tile-sized, QBLK-independent) -> duplication cost ~0.
// LDS 32 KB -> 5 blocks/CU; occupancy 12 -> 20 waves/CU. r13/r17 softmax structure.
__global__ __launch_bounds__(256, 4) void attn_kernel(
    const ushort* __restrict__ qbuf, const ushort* __restrict__ kbuf,
    const ushort* __restrict__ vtbuf, const ushort* __restrict__ biash,
    ushort* __restrict__ attn_out)
{
    __shared__ ushort Ks[2][64 * 64];    // K [kv][hd] bf16, unpadded, swizzled, dbuf
    __shared__ ushort Vt[2][64 * 64];    // V^T [hd][kv] fp16, unpadded, swizzled, dbuf

    const int t = threadIdx.x;
    const int w = t >> 6, l = t & 63;
    const int lr = l & 15, lg = l >> 4;

    const int bid = blockIdx.x;
    const int lid = (bid & 7) * 192 + (bid >> 3);  // XCD-chunked swizzle (1.5 heads/XCD -> 3MB bias in L2)
    const int h  = lid >> 7;
    const int qt = (lid >> 3) & 15;
    const int b  = lid & 7;

    const int q0 = qt * 64;
    const size_t headoff = (size_t)(b * HEADS + h) * SEQ * HD;
    const int qrb = q0 + w * 16;         // each wave owns 16 q rows

    // Q fragments (pre-scaled by 0.125*log2e)
    bfrag aQ0, aQ1;
    {
        const ushort* Qp = qbuf + headoff + (size_t)(qrb + lr) * HD;
        aQ0 = *(const bfrag*)(Qp + lg * 8);
        aQ1 = *(const bfrag*)(Qp + 32 + lg * 8);
    }

    float mrun = -1e30f;
    float lrun = 0.0f;                   // per-lane partial; reduced in epilogue
    facc Ov[4] = {};

    const ushort* bprow = biash + ((size_t)h * SEQ + qrb + lr) * SEQ;

    const ushort* kbh  = kbuf  + headoff;                         // [kv][64] bf16
    const ushort* vtbh = vtbuf + (size_t)(b * HEADS + h) * 65536; // [d][1024] fp16
    const int srow = (w << 3) + (l >> 3);
    const int sgr  = ((l & 7) ^ (srow & 7)) << 3;                 // src granule offset (ushorts)

    const int g0 = (lg ^ (lr & 7)) << 3;                          // K granule for kf0

    // ---- prologue: DMA tile0, bias0 ----
    GLOAD16(kbh + (size_t)srow * 64 + sgr,            &Ks[0][w * 512]);
    GLOAD16(kbh + (size_t)(srow + 32) * 64 + sgr,     &Ks[0][2048 + w * 512]);
    GLOAD16(vtbh + (size_t)srow * 1024 + sgr,         &Vt[0][w * 512]);
    GLOAD16(vtbh + (size_t)(srow + 32) * 1024 + sgr,  &Vt[0][2048 + w * 512]);
    uint2 bcur[4];
#pragma unroll
    for (int c = 0; c < 4; ++c)
        bcur[c] = *(const uint2*)(bprow + c * 16 + lg * 4);
    __syncthreads();

    for (int tt = 0; tt < 16; ++tt) {
        const int cur = tt & 1;
        const ushort* Kc = Ks[cur];
        const ushort* Vc = Vt[cur];

        // (0) issue DMA for tile tt+1 into the other buffer
        if (tt < 15) {
            const int kvn = (tt + 1) << 6;
            GLOAD16(kbh + (size_t)(kvn + srow) * 64 + sgr,           &Ks[cur ^ 1][w * 512]);
            GLOAD16(kbh + (size_t)(kvn + srow + 32) * 64 + sgr,      &Ks[cur ^ 1][2048 + w * 512]);
            GLOAD16(vtbh + (size_t)srow * 1024 + kvn + sgr,          &Vt[cur ^ 1][w * 512]);
            GLOAD16(vtbh + (size_t)(srow + 32) * 1024 + kvn + sgr,   &Vt[cur ^ 1][2048 + w * 512]);
        }

        // (1) QK^T (C-init = fp16 bias, pre-scaled) fused with stale-max raw exp2
        facc St[4];
        h4 pf[4];
        float psum = 0.0f, pmax = -3.0e38f;
#pragma unroll
        for (int c = 0; c < 4; ++c) {
            bfrag kf0 = *(const bfrag*)&Kc[(c * 16 + lr) * 64 + g0];
            bfrag kf1 = *(const bfrag*)&Kc[(c * 16 + lr) * 64 + (g0 ^ 32)];
            uint2 bb = bcur[c];
            facc s;
            s[0] = h2f(bb.x & 0xffffu);
            s[1] = h2f(bb.x >> 16);
            s[2] = h2f(bb.y & 0xffffu);
            s[3] = h2f(bb.y >> 16);
            __builtin_amdgcn_s_setprio(1);
            s = __builtin_amdgcn_mfma_f32_16x16x32_bf16(kf0, aQ0, s, 0, 0, 0);
            s = __builtin_amdgcn_mfma_f32_16x16x32_bf16(kf1, aQ1, s, 0, 0, 0);
            __builtin_amdgcn_s_setprio(0);
            St[c] = s;
            float p0 = exp2_raw(s[0] - mrun);
            float p1 = exp2_raw(s[1] - mrun);
            float p2f = exp2_raw(s[2] - mrun);
            float p3 = exp2_raw(s[3] - mrun);
            psum += (p0 + p1) + (p2f + p3);
            pmax = fmaxf(pmax, fmaxf(fmaxf(s[0], s[1]), fmaxf(s[2], s[3])));
            pf[c] = pack4h(p0, p1, p2f, p3);
        }

        // bias prefetch for tile tt+1 (bcur dead after C-init above)
        if (tt < 15) {
            const int kvn = (tt + 1) << 6;
#pragma unroll
            for (int c = 0; c < 4; ++c)
                bcur[c] = *(const uint2*)(bprow + kvn + c * 16 + lg * 4);
        }

        // defer-max check: per-lane LOCAL (shallow dep chain); __any makes it wave-uniform.
        if (__any(pmax > mrun + 14.0f)) {
            float pm = pmax;
            pm = fmaxf(pm, __shfl_xor(pm, 16));
            pm = fmaxf(pm, __shfl_xor(pm, 32));
            float mnew = fmaxf(mrun, pm);
            float al = exp2_raw(mrun - mnew);
            psum = 0.0f;
#pragma unroll
            for (int c = 0; c < 4; ++c) {
                float p0 = exp2_raw(St[c][0] - mnew);
                float p1 = exp2_raw(St[c][1] - mnew);
                float p2f = exp2_raw(St[c][2] - mnew);
                float p3 = exp2_raw(St[c][3] - mnew);
                psum += (p0 + p1) + (p2f + p3);
                pf[c] = pack4h(p0, p1, p2f, p3);
            }
#pragma unroll
            for (int r = 0; r < 4; ++r) {
                float a = __shfl(al, lg * 4 + r);
#pragma unroll
                for (int d = 0; d < 4; ++d) Ov[d][r] *= a;
            }
            lrun *= al;
            mrun = mnew;
        }

        // (4) PV: c outer (4 distinct accumulators). V^T swizzled 8B reads.
        __builtin_amdgcn_s_setprio(1);
#pragma unroll
        for (int c = 0; c < 4; ++c) {
#pragma unroll
            for (int d0 = 0; d0 < 4; ++d0) {
                int row = d0 * 16 + lr;
                h4 bv = *(const h4*)&Vc[row * 64 + ((((c * 2 + (lg >> 1)) ^ (lr & 7)) << 3) + ((lg & 1) << 2))];
                Ov[d0] = __builtin_amdgcn_mfma_f32_16x16x16f16(pf[c], bv, Ov[d0], 0, 0, 0);
            }
        }
        __builtin_amdgcn_s_setprio(0);

        lrun += psum;   // per-lane partial, off the pre-PV critical path

        // (5) single barrier per tile (implicit vmcnt(0) drains the tt+1 DMA)
        if (tt < 15) __syncthreads();
    }

    // epilogue: reduce lrun partials (once), normalize, write [b][n][h*64+d] bf16
    float lt = lrun;
    lt += __shfl_xor(lt, 16);
    lt += __shfl_xor(lt, 32);
    ushort* op = attn_out + ((size_t)b * SEQ + qrb) * CDIM + h * HD;
#pragma unroll
    for (int r = 0; r < 4; ++r) {
        float ll = __shfl(lt, lg * 4 + r);
        float rl = 1.0f / ll;
#pragma unroll
        for (int d = 0; d < 4; ++d)
            op[(size_t)(lg * 4 + r) * CDIM + d * 16 + lr] = f2bf(Ov[d][r] * rl);
    }
}

// ---------------- launch ----------------
extern "C" void kernel_launch(void* const* d_in, const int* in_sizes, int n_in,
                              void* d_out, int out_size, void* d_ws, size_t ws_size,
                              hipStream_t stream) {
    const float* x     = (const float*)d_in[0];   // (8,1024,768)
    const float* rel   = (const float*)d_in[1];   // (12,1024,1024)
    const float* qkvw  = (const float*)d_in[2];   // (2304,768)
    const float* projw = (const float*)d_in[3];   // (768,768)
    const float* projb = (const float*)d_in[4];   // (768,)
    float* out = (float*)d_out;

    // Workspace (80,216,064 B). attnb aliases xbf (xbf dead after gemm<0>).
    char* ws = (char*)d_ws;
    ushort* biash = (ushort*)(ws);                 // 12,582,912 halves (fp16, *log2e)
    ushort* qb    = (ushort*)(ws + 25165824);      // bf16 [bh][n][d]
    ushort* kb    = (ushort*)(ws + 37748736);      // bf16 [bh][n][d]
    ushort* vb    = (ushort*)(ws + 50331648);      // fp16 TRANSPOSED [bh][d][n]
    ushort* attnb = (ushort*)(ws + 62914560);      // bf16 (aliases xbf)
    ushort* xbf   = attnb;
    ushort* wbf   = (ushort*)(ws + 75497472);
    ushort* pwbf  = (ushort*)(ws + 79036416);

    cvt_all<<<8448, 256, 0, stream>>>(x, qkvw, projw, xbf, wbf, pwbf);

    // gemm0: y<4 = 256 long-running bias-convert blocks (dispatched first, overlap gemm compute)
    gemm_nt<0><<<dim3(64, 22), 256, 0, stream>>>(xbf, wbf, qb, kb, vb, nullptr, nullptr, rel, biash);
    attn_kernel<<<1536, 256, 0, stream>>>(qb, kb, vb, biash, attnb);
    gemm_nt<1><<<dim3(64, 6), 256, 0, stream>>>(attnb, pwbf, nullptr, nullptr, nullptr, projb, out, nullptr, nullptr);
}

// Round 20
// 139.642 us; speedup vs baseline: 1.0381x; 1.0381x over previous
//
#include <hip/hip_runtime.h>
#include <hip/hip_bf16.h>
#include <stdint.h>

#define HEADS 12
#define HD 64
#define SEQ 1024
#define CDIM 768
#define LOG2E 1.44269504f

typedef __attribute__((ext_vector_type(8))) short bfrag;     // 8 bf16 (4 VGPRs)
typedef __attribute__((ext_vector_type(4))) float facc;      // 4 fp32 accum
typedef __attribute__((ext_vector_type(4))) _Float16 h4;     // 4 fp16 (2 VGPRs)
typedef __attribute__((ext_vector_type(2))) __fp16 pk2;      // cvt_pkrtz result type

__device__ __forceinline__ ushort f2bf(float f) {
    union { float f; uint32_t u; } v; v.f = f;
    uint32_t u = v.u;
    uint32_t r = (u + 0x7FFFu + ((u >> 16) & 1u)) >> 16;
    return (ushort)r;
}
__device__ __forceinline__ ushort f2h(float f) {
    union { _Float16 h; ushort u; } c; c.h = (_Float16)f; return c.u;
}
__device__ __forceinline__ float h2f(uint32_t u16) {
    union { _Float16 h; ushort u; } c; c.u = (ushort)u16; return (float)c.h;
}
__device__ __forceinline__ h4 pack4h(float p0, float p1, float p2, float p3) {
    union { h4 v4; pk2 v2[2]; } u;
    u.v2[0] = __builtin_amdgcn_cvt_pkrtz(p0, p1);
    u.v2[1] = __builtin_amdgcn_cvt_pkrtz(p2, p3);
    return u.v4;
}
// bare v_exp_f32 (2^x) — avoids libm exp2 range-fixup expansion
__device__ __forceinline__ float exp2_raw(float x) {
    float r;
    asm("v_exp_f32 %0, %1" : "=v"(r) : "v"(x));
    return r;
}

// ---------------- fused fp32 -> bf16 converts (x, qkv_w, proj_w) ----------------
__global__ void cvt_all(const float* __restrict__ x, const float* __restrict__ qw,
                        const float* __restrict__ pw,
                        ushort* __restrict__ xd, ushort* __restrict__ qd,
                        ushort* __restrict__ pd) {
    long i = ((long)blockIdx.x * 256 + threadIdx.x) * 4;
    if (i < 6291456) {
        float4 v = *(const float4*)(x + i);
        ushort4 o = {f2bf(v.x), f2bf(v.y), f2bf(v.z), f2bf(v.w)};
        *(ushort4*)(xd + i) = o;
    } else if (i < 8060928) {
        long j = i - 6291456;
        float4 v = *(const float4*)(qw + j);
        ushort4 o = {f2bf(v.x), f2bf(v.y), f2bf(v.z), f2bf(v.w)};
        *(ushort4*)(qd + j) = o;
    } else if (i < 8650752) {
        long j = i - 8060928;
        float4 v = *(const float4*)(pw + j);
        ushort4 o = {f2bf(v.x), f2bf(v.y), f2bf(v.z), f2bf(v.w)};
        *(ushort4*)(pd + j) = o;
    }
}

#define GLOAD16(gsrc, ldst) \
    __builtin_amdgcn_global_load_lds((const __attribute__((address_space(1))) uint32_t*)(gsrc), \
                                     (__attribute__((address_space(3))) uint32_t*)(ldst), 16, 0, 0)

// ---------------- NT GEMM, 128x128 tile, BK=64, swizzled DMA staging ----------------
// LDS [128][64] linear dest; 16B-granule XOR swizzle: DMA src granule (l&7)^(l>>3),
// read granule (s*4+lg)^(lr&7) -> 2-way (free) bank access (rule #21 both-sides).
// EPI 0: grid (64, 22). y<4: 256 grid-stride rel->fp16*log2e convert blocks (dispatched first).
//        y>=4: gemm tile. Scatter q (bf16, *0.125*log2e), k (bf16), v TRANSPOSED (fp16 [bh][d][seq]).
// EPI 1: out fp32 += proj bias (grid (64, 6))
template<int EPI>
__global__ __launch_bounds__(256) void gemm_nt(
    const ushort* __restrict__ A, const ushort* __restrict__ Bm,
    ushort* __restrict__ qb, ushort* __restrict__ kb, ushort* __restrict__ vb,
    const float* __restrict__ projb, float* __restrict__ out,
    const float* __restrict__ relf, ushort* __restrict__ biash)
{
    __shared__ ushort As[128 * 64];
    __shared__ ushort Bs[128 * 64];
    const int t = threadIdx.x;

    int m0, o0;
    if (EPI == 0) {
        if (blockIdx.y < 4) {
            const int cb = blockIdx.y * 64 + blockIdx.x;    // 0..255
#pragma unroll 4
            for (int s = 0; s < 48; ++s) {
                long i = (((long)s * 256 + cb) * 256 + t) * 4;
                float4 v = *(const float4*)(relf + i);
                ushort4 o = {f2h(v.x * LOG2E), f2h(v.y * LOG2E),
                             f2h(v.z * LOG2E), f2h(v.w * LOG2E)};
                *(ushort4*)(biash + i) = o;
            }
            return;
        }
        m0 = blockIdx.x * 128;
        o0 = (blockIdx.y - 4) * 128;
    } else {
        m0 = blockIdx.x * 128;
        o0 = blockIdx.y * 128;
    }

    const int w = t >> 6, l = t & 63;
    const int wm = w >> 1, wn = w & 1;
    const int lr = l & 15, lg = l >> 4;

    facc acc[4][4] = {};

    const int srow = w * 8 + (l >> 3);
    const int sgr  = ((l & 7) ^ (l >> 3)) * 8;
    const ushort* Ag = A + (size_t)(m0 + srow) * CDIM + sgr;
    const ushort* Bg = Bm + (size_t)(o0 + srow) * CDIM + sgr;
    const int ldst = w * 512 + l * 8;                 // + j*2048

    for (int k0 = 0; k0 < CDIM; k0 += 64) {
        __syncthreads();
#pragma unroll
        for (int j = 0; j < 4; ++j) {
            GLOAD16(Ag + (size_t)(j * 32) * CDIM + k0, As + j * 2048 + ldst);
            GLOAD16(Bg + (size_t)(j * 32) * CDIM + k0, Bs + j * 2048 + ldst);
        }
        __syncthreads();
#pragma unroll
        for (int s = 0; s < 2; ++s) {
            bfrag af[4], bf[4];
            const int rg = ((s * 4 + lg) ^ (lr & 7)) * 8;   // swizzled read granule
#pragma unroll
            for (int m = 0; m < 4; ++m)
                af[m] = *(const bfrag*)&As[(wm * 64 + m * 16 + lr) * 64 + rg];
#pragma unroll
            for (int n = 0; n < 4; ++n)
                bf[n] = *(const bfrag*)&Bs[(wn * 64 + n * 16 + lr) * 64 + rg];
#pragma unroll
            for (int m = 0; m < 4; ++m)
#pragma unroll
                for (int n = 0; n < 4; ++n)
                    acc[m][n] = __builtin_amdgcn_mfma_f32_16x16x32_bf16(af[m], bf[n], acc[m][n], 0, 0, 0);
        }
    }

    if (EPI == 0) {
        const int tsel = o0 / CDIM;
        const int h_base = (o0 % CDIM) / 64;
        if (tsel == 2) {
            // V TRANSPOSED: vb[bh][d][seq] fp16, vectorized over 4 consecutive seq (r)
#pragma unroll
            for (int m = 0; m < 4; ++m) {
                int grow = m0 + wm * 64 + m * 16 + lg * 4;
                int b = grow >> 10, nn = grow & 1023;
#pragma unroll
                for (int n = 0; n < 4; ++n) {
                    int h = h_base + wn;
                    int d = n * 16 + lr;
                    ushort4 pk = {f2h(acc[m][n][0]), f2h(acc[m][n][1]),
                                  f2h(acc[m][n][2]), f2h(acc[m][n][3])};
                    *(ushort4*)&vb[(((size_t)(b * HEADS + h)) * 64 + d) * 1024 + nn] = pk;
                }
            }
        } else {
            ushort* dst = (tsel == 0) ? qb : kb;
            const float scl = (tsel == 0) ? 0.18033688f : 1.0f;   // 0.125 * log2(e)
#pragma unroll
            for (int m = 0; m < 4; ++m) {
                int grow = m0 + wm * 64 + m * 16 + lg * 4;
#pragma unroll
                for (int n = 0; n < 4; ++n) {
                    int h = h_base + wn;
                    int d = n * 16 + lr;
#pragma unroll
                    for (int r = 0; r < 4; ++r) {
                        int row = grow + r;
                        int b = row >> 10, nn = row & 1023;
                        dst[(((size_t)(b * HEADS + h)) * SEQ + nn) * HD + d] = f2bf(acc[m][n][r] * scl);
                    }
                }
            }
        }
    } else {
#pragma unroll
        for (int m = 0; m < 4; ++m) {
            int grow = m0 + wm * 64 + m * 16 + lg * 4;
#pragma unroll
            for (int n = 0; n < 4; ++n) {
                int o = o0 + wn * 64 + n * 16 + lr;
                float bias = projb[o];
#pragma unroll
                for (int r = 0; r < 4; ++r)
                    out[(size_t)(grow + r) * CDIM + o] = acc[m][n][r] + bias;
            }
        }
    }
}

// ---------------- fused flash attention: DMA-staged K/V^T with XOR swizzle [r17/r18 best] ----------------
__global__ __launch_bounds__(256, 3) void attn_kernel(
    const ushort* __restrict__ qbuf, const ushort* __restrict__ kbuf,
    const ushort* __restrict__ vtbuf, const ushort* __restrict__ biash,
    ushort* __restrict__ attn_out)
{
    __shared__ ushort Ks[2][64 * 64];    // K [kv][hd] bf16, unpadded, swizzled, dbuf
    __shared__ ushort Vt[2][64 * 64];    // V^T [hd][kv] fp16, unpadded, swizzled, dbuf

    const int t = threadIdx.x;
    const int w = t >> 6, l = t & 63;
    const int lr = l & 15, lg = l >> 4;

    const int bid = blockIdx.x;
    const int lid = (bid & 7) * 96 + (bid >> 3);   // XCD-chunked swizzle
    const int h  = lid >> 6;
    const int qt = (lid >> 3) & 7;
    const int b  = lid & 7;

    const int q0 = qt * 128;
    const size_t headoff = (size_t)(b * HEADS + h) * SEQ * HD;
    const int qrb = q0 + w * 32;

    // Q fragments (pre-scaled by 0.125*log2e)
    bfrag aQ[2][2];
#pragma unroll
    for (int n = 0; n < 2; ++n) {
        const ushort* Qp = qbuf + headoff + (size_t)(qrb + n * 16 + lr) * HD;
        aQ[n][0] = *(const bfrag*)(Qp + lg * 8);
        aQ[n][1] = *(const bfrag*)(Qp + 32 + lg * 8);
    }

    float mrun[2] = {-1e30f, -1e30f};
    float lrun[2] = {0.0f, 0.0f};        // PER-LANE partial; reduced in epilogue
    facc Ov[2][4] = {};

    const ushort* bprow[2];
#pragma unroll
    for (int n = 0; n < 2; ++n)
        bprow[n] = biash + ((size_t)h * SEQ + qrb + n * 16 + lr) * SEQ;

    const ushort* kbh  = kbuf  + headoff;                         // [kv][64] bf16
    const ushort* vtbh = vtbuf + (size_t)(b * HEADS + h) * 65536; // [d][1024] fp16
    const int srow = (w << 3) + (l >> 3);
    const int sgr  = ((l & 7) ^ (srow & 7)) << 3;                 // src granule offset (ushorts)

    const int g0 = (lg ^ (lr & 7)) << 3;                          // K granule for kf0

    // ---- prologue: DMA tile0 ----
    GLOAD16(kbh + (size_t)srow * 64 + sgr,            &Ks[0][w * 512]);
    GLOAD16(kbh + (size_t)(srow + 32) * 64 + sgr,     &Ks[0][2048 + w * 512]);
    GLOAD16(vtbh + (size_t)srow * 1024 + sgr,         &Vt[0][w * 512]);
    GLOAD16(vtbh + (size_t)(srow + 32) * 1024 + sgr,  &Vt[0][2048 + w * 512]);
    uint2 bcur[2][4];
#pragma unroll
    for (int n = 0; n < 2; ++n)
#pragma unroll
        for (int c = 0; c < 4; ++c)
            bcur[n][c] = *(const uint2*)(bprow[n] + c * 16 + lg * 4);
    __syncthreads();

    for (int tt = 0; tt < 16; ++tt) {
        const int cur = tt & 1;
        const ushort* Kc = Ks[cur];
        const ushort* Vc = Vt[cur];

        // (0) issue DMA for tile tt+1 into the other buffer
        if (tt < 15) {
            const int kvn = (tt + 1) << 6;
            GLOAD16(kbh + (size_t)(kvn + srow) * 64 + sgr,           &Ks[cur ^ 1][w * 512]);
            GLOAD16(kbh + (size_t)(kvn + srow + 32) * 64 + sgr,      &Ks[cur ^ 1][2048 + w * 512]);
            GLOAD16(vtbh + (size_t)srow * 1024 + kvn + sgr,          &Vt[cur ^ 1][w * 512]);
            GLOAD16(vtbh + (size_t)(srow + 32) * 1024 + kvn + sgr,   &Vt[cur ^ 1][2048 + w * 512]);
        }

        // (1) QK^T (C-init = fp16 bias, pre-scaled) fused with stale-max raw exp2
        facc St[2][4];
        h4 pf[2][4];
        float psum[2] = {0.0f, 0.0f};
        float pmax[2] = {-3.0e38f, -3.0e38f};
#pragma unroll
        for (int c = 0; c < 4; ++c) {
            bfrag kf0 = *(const bfrag*)&Kc[(c * 16 + lr) * 64 + g0];
            bfrag kf1 = *(const bfrag*)&Kc[(c * 16 + lr) * 64 + (g0 ^ 32)];
#pragma unroll
            for (int n = 0; n < 2; ++n) {
                uint2 bb = bcur[n][c];
                facc s;
                s[0] = h2f(bb.x & 0xffffu);
                s[1] = h2f(bb.x >> 16);
                s[2] = h2f(bb.y & 0xffffu);
                s[3] = h2f(bb.y >> 16);
                __builtin_amdgcn_s_setprio(1);
                s = __builtin_amdgcn_mfma_f32_16x16x32_bf16(kf0, aQ[n][0], s, 0, 0, 0);
                s = __builtin_amdgcn_mfma_f32_16x16x32_bf16(kf1, aQ[n][1], s, 0, 0, 0);
                __builtin_amdgcn_s_setprio(0);
                St[n][c] = s;
                float p0 = exp2_raw(s[0] - mrun[n]);
                float p1 = exp2_raw(s[1] - mrun[n]);
                float p2f = exp2_raw(s[2] - mrun[n]);
                float p3 = exp2_raw(s[3] - mrun[n]);
                psum[n] += (p0 + p1) + (p2f + p3);
                pmax[n] = fmaxf(pmax[n], fmaxf(fmaxf(s[0], s[1]), fmaxf(s[2], s[3])));
                pf[n][c] = pack4h(p0, p1, p2f, p3);
            }
        }

        // bias prefetch for tile tt+1 (bcur dead after C-init above)
        if (tt < 15) {
            const int kvn = (tt + 1) << 6;
#pragma unroll
            for (int n = 0; n < 2; ++n)
#pragma unroll
                for (int c = 0; c < 4; ++c)
                    bcur[n][c] = *(const uint2*)(bprow[n] + kvn + c * 16 + lg * 4);
        }

        // defer-max check: per-lane LOCAL (shallow dep chain); __any makes it wave-uniform.
        int viol = (pmax[0] > mrun[0] + 14.0f) || (pmax[1] > mrun[1] + 14.0f);
        if (__any(viol)) {
#pragma unroll
            for (int n = 0; n < 2; ++n) {
                float pm = pmax[n];
                pm = fmaxf(pm, __shfl_xor(pm, 16));
                pm = fmaxf(pm, __shfl_xor(pm, 32));
                float mnew = fmaxf(mrun[n], pm);
                float al = exp2_raw(mrun[n] - mnew);
                psum[n] = 0.0f;
#pragma unroll
                for (int c = 0; c < 4; ++c) {
                    float p0 = exp2_raw(St[n][c][0] - mnew);
                    float p1 = exp2_raw(St[n][c][1] - mnew);
                    float p2f = exp2_raw(St[n][c][2] - mnew);
                    float p3 = exp2_raw(St[n][c][3] - mnew);
                    psum[n] += (p0 + p1) + (p2f + p3);
                    pf[n][c] = pack4h(p0, p1, p2f, p3);
                }
#pragma unroll
                for (int r = 0; r < 4; ++r) {
                    float a = __shfl(al, lg * 4 + r);
#pragma unroll
                    for (int d = 0; d < 4; ++d) Ov[n][d][r] *= a;
                }
                lrun[n] *= al;
                mrun[n] = mnew;
            }
        }

        // (4) PV: c outer (8 distinct accumulators). V^T swizzled 8B reads.
        __builtin_amdgcn_s_setprio(1);
#pragma unroll
        for (int c = 0; c < 4; ++c) {
#pragma unroll
            for (int d0 = 0; d0 < 4; ++d0) {
                int row = d0 * 16 + lr;
                h4 bv = *(const h4*)&Vc[row * 64 + ((((c * 2 + (lg >> 1)) ^ (lr & 7)) << 3) + ((lg & 1) << 2))];
#pragma unroll
                for (int n = 0; n < 2; ++n)
                    Ov[n][d0] = __builtin_amdgcn_mfma_f32_16x16x16f16(pf[n][c], bv, Ov[n][d0], 0, 0, 0);
            }
        }
        __builtin_amdgcn_s_setprio(0);

        lrun[0] += psum[0];
        lrun[1] += psum[1];

        // (5) single barrier per tile (implicit vmcnt(0) drains the tt+1 DMA)
        if (tt < 15) __syncthreads();
    }

    // epilogue: reduce lrun partials (once), normalize, write
#pragma unroll
    for (int n = 0; n < 2; ++n) {
        float lt = lrun[n];
        lt += __shfl_xor(lt, 16);
        lt += __shfl_xor(lt, 32);
        ushort* op = attn_out + ((size_t)b * SEQ + qrb + n * 16) * CDIM + h * HD;
#pragma unroll
        for (int r = 0; r < 4; ++r) {
            float ll = __shfl(lt, lg * 4 + r);
            float rl = 1.0f / ll;
#pragma unroll
            for (int d = 0; d < 4; ++d)
                op[(size_t)(lg * 4 + r) * CDIM + d * 16 + lr] = f2bf(Ov[n][d][r] * rl);
        }
    }
}

// ---------------- launch ----------------
extern "C" void kernel_launch(void* const* d_in, const int* in_sizes, int n_in,
                              void* d_out, int out_size, void* d_ws, size_t ws_size,
                              hipStream_t stream) {
    const float* x     = (const float*)d_in[0];   // (8,1024,768)
    const float* rel   = (const float*)d_in[1];   // (12,1024,1024)
    const float* qkvw  = (const float*)d_in[2];   // (2304,768)
    const float* projw = (const float*)d_in[3];   // (768,768)
    const float* projb = (const float*)d_in[4];   // (768,)
    float* out = (float*)d_out;

    // Workspace (80,216,064 B). attnb aliases xbf (xbf dead after gemm<0>).
    char* ws = (char*)d_ws;
    ushort* biash = (ushort*)(ws);                 // 12,582,912 halves (fp16, *log2e)
    ushort* qb    = (ushort*)(ws + 25165824);      // bf16 [bh][n][d]
    ushort* kb    = (ushort*)(ws + 37748736);      // bf16 [bh][n][d]
    ushort* vb    = (ushort*)(ws + 50331648);      // fp16 TRANSPOSED [bh][d][n]
    ushort* attnb = (ushort*)(ws + 62914560);      // bf16 (aliases xbf)
    ushort* xbf   = attnb;
    ushort* wbf   = (ushort*)(ws + 75497472);
    ushort* pwbf  = (ushort*)(ws + 79036416);

    cvt_all<<<8448, 256, 0, stream>>>(x, qkvw, projw, xbf, wbf, pwbf);

    // gemm0: y<4 = 256 long-running bias-convert blocks (dispatched first, overlap gemm compute)
    gemm_nt<0><<<dim3(64, 22), 256, 0, stream>>>(xbf, wbf, qb, kb, vb, nullptr, nullptr, rel, biash);
    attn_kernel<<<768, 256, 0, stream>>>(qb, kb, vb, biash, attnb);
    gemm_nt<1><<<dim3(64, 6), 256, 0, stream>>>(attnb, pwbf, nullptr, nullptr, nullptr, projb, out, nullptr, nullptr);
}

// Round 21
// 137.643 us; speedup vs baseline: 1.0532x; 1.0145x over previous
//
#include <hip/hip_runtime.h>
#include <hip/hip_bf16.h>
#include <stdint.h>

#define HEADS 12
#define HD 64
#define SEQ 1024
#define CDIM 768
#define LOG2E 1.44269504f

typedef __attribute__((ext_vector_type(8))) short bfrag;     // 8 bf16 (4 VGPRs)
typedef __attribute__((ext_vector_type(4))) float facc;      // 4 fp32 accum
typedef __attribute__((ext_vector_type(4))) _Float16 h4;     // 4 fp16 (2 VGPRs)
typedef __attribute__((ext_vector_type(2))) __fp16 pk2;      // cvt_pkrtz result type

__device__ __forceinline__ ushort f2bf(float f) {
    union { float f; uint32_t u; } v; v.f = f;
    uint32_t u = v.u;
    uint32_t r = (u + 0x7FFFu + ((u >> 16) & 1u)) >> 16;
    return (ushort)r;
}
__device__ __forceinline__ ushort f2h(float f) {
    union { _Float16 h; ushort u; } c; c.h = (_Float16)f; return c.u;
}
__device__ __forceinline__ float h2f(uint32_t u16) {
    union { _Float16 h; ushort u; } c; c.u = (ushort)u16; return (float)c.h;
}
__device__ __forceinline__ h4 pack4h(float p0, float p1, float p2, float p3) {
    union { h4 v4; pk2 v2[2]; } u;
    u.v2[0] = __builtin_amdgcn_cvt_pkrtz(p0, p1);
    u.v2[1] = __builtin_amdgcn_cvt_pkrtz(p2, p3);
    return u.v4;
}
// bare v_exp_f32 (2^x) — avoids libm exp2 range-fixup expansion
__device__ __forceinline__ float exp2_raw(float x) {
    float r;
    asm("v_exp_f32 %0, %1" : "=v"(r) : "v"(x));
    return r;
}

// ---------------- fused fp32 -> bf16 converts (x, qkv_w, proj_w) ----------------
__global__ void cvt_all(const float* __restrict__ x, const float* __restrict__ qw,
                        const float* __restrict__ pw,
                        ushort* __restrict__ xd, ushort* __restrict__ qd,
                        ushort* __restrict__ pd) {
    long i = ((long)blockIdx.x * 256 + threadIdx.x) * 4;
    if (i < 6291456) {
        float4 v = *(const float4*)(x + i);
        ushort4 o = {f2bf(v.x), f2bf(v.y), f2bf(v.z), f2bf(v.w)};
        *(ushort4*)(xd + i) = o;
    } else if (i < 8060928) {
        long j = i - 6291456;
        float4 v = *(const float4*)(qw + j);
        ushort4 o = {f2bf(v.x), f2bf(v.y), f2bf(v.z), f2bf(v.w)};
        *(ushort4*)(qd + j) = o;
    } else if (i < 8650752) {
        long j = i - 8060928;
        float4 v = *(const float4*)(pw + j);
        ushort4 o = {f2bf(v.x), f2bf(v.y), f2bf(v.z), f2bf(v.w)};
        *(ushort4*)(pd + j) = o;
    }
}

#define GLOAD16(gsrc, ldst) \
    __builtin_amdgcn_global_load_lds((const __attribute__((address_space(1))) uint32_t*)(gsrc), \
                                     (__attribute__((address_space(3))) uint32_t*)(ldst), 16, 0, 0)

// ---------------- NT GEMM, 128x128 tile, BK=64, swizzled DMA staging [r18, frozen] ----------------
template<int EPI>
__global__ __launch_bounds__(256) void gemm_nt(
    const ushort* __restrict__ A, const ushort* __restrict__ Bm,
    ushort* __restrict__ qb, ushort* __restrict__ kb, ushort* __restrict__ vb,
    const float* __restrict__ projb, float* __restrict__ out,
    const float* __restrict__ relf, ushort* __restrict__ biash)
{
    __shared__ ushort As[128 * 64];
    __shared__ ushort Bs[128 * 64];
    const int t = threadIdx.x;

    int m0, o0;
    if (EPI == 0) {
        if (blockIdx.y < 4) {
            const int cb = blockIdx.y * 64 + blockIdx.x;    // 0..255
#pragma unroll 4
            for (int s = 0; s < 48; ++s) {
                long i = (((long)s * 256 + cb) * 256 + t) * 4;
                float4 v = *(const float4*)(relf + i);
                ushort4 o = {f2h(v.x * LOG2E), f2h(v.y * LOG2E),
                             f2h(v.z * LOG2E), f2h(v.w * LOG2E)};
                *(ushort4*)(biash + i) = o;
            }
            return;
        }
        m0 = blockIdx.x * 128;
        o0 = (blockIdx.y - 4) * 128;
    } else {
        m0 = blockIdx.x * 128;
        o0 = blockIdx.y * 128;
    }

    const int w = t >> 6, l = t & 63;
    const int wm = w >> 1, wn = w & 1;
    const int lr = l & 15, lg = l >> 4;

    facc acc[4][4] = {};

    const int srow = w * 8 + (l >> 3);
    const int sgr  = ((l & 7) ^ (l >> 3)) * 8;
    const ushort* Ag = A + (size_t)(m0 + srow) * CDIM + sgr;
    const ushort* Bg = Bm + (size_t)(o0 + srow) * CDIM + sgr;
    const int ldst = w * 512 + l * 8;                 // + j*2048

    for (int k0 = 0; k0 < CDIM; k0 += 64) {
        __syncthreads();
#pragma unroll
        for (int j = 0; j < 4; ++j) {
            GLOAD16(Ag + (size_t)(j * 32) * CDIM + k0, As + j * 2048 + ldst);
            GLOAD16(Bg + (size_t)(j * 32) * CDIM + k0, Bs + j * 2048 + ldst);
        }
        __syncthreads();
#pragma unroll
        for (int s = 0; s < 2; ++s) {
            bfrag af[4], bf[4];
            const int rg = ((s * 4 + lg) ^ (lr & 7)) * 8;   // swizzled read granule
#pragma unroll
            for (int m = 0; m < 4; ++m)
                af[m] = *(const bfrag*)&As[(wm * 64 + m * 16 + lr) * 64 + rg];
#pragma unroll
            for (int n = 0; n < 4; ++n)
                bf[n] = *(const bfrag*)&Bs[(wn * 64 + n * 16 + lr) * 64 + rg];
#pragma unroll
            for (int m = 0; m < 4; ++m)
#pragma unroll
                for (int n = 0; n < 4; ++n)
                    acc[m][n] = __builtin_amdgcn_mfma_f32_16x16x32_bf16(af[m], bf[n], acc[m][n], 0, 0, 0);
        }
    }

    if (EPI == 0) {
        const int tsel = o0 / CDIM;
        const int h_base = (o0 % CDIM) / 64;
        if (tsel == 2) {
            // V TRANSPOSED: vb[bh][d][seq] fp16, vectorized over 4 consecutive seq (r)
#pragma unroll
            for (int m = 0; m < 4; ++m) {
                int grow = m0 + wm * 64 + m * 16 + lg * 4;
                int b = grow >> 10, nn = grow & 1023;
#pragma unroll
                for (int n = 0; n < 4; ++n) {
                    int h = h_base + wn;
                    int d = n * 16 + lr;
                    ushort4 pk = {f2h(acc[m][n][0]), f2h(acc[m][n][1]),
                                  f2h(acc[m][n][2]), f2h(acc[m][n][3])};
                    *(ushort4*)&vb[(((size_t)(b * HEADS + h)) * 64 + d) * 1024 + nn] = pk;
                }
            }
        } else {
            ushort* dst = (tsel == 0) ? qb : kb;
            const float scl = (tsel == 0) ? 0.18033688f : 1.0f;   // 0.125 * log2(e)
#pragma unroll
            for (int m = 0; m < 4; ++m) {
                int grow = m0 + wm * 64 + m * 16 + lg * 4;
#pragma unroll
                for (int n = 0; n < 4; ++n) {
                    int h = h_base + wn;
                    int d = n * 16 + lr;
#pragma unroll
                    for (int r = 0; r < 4; ++r) {
                        int row = grow + r;
                        int b = row >> 10, nn = row & 1023;
                        dst[(((size_t)(b * HEADS + h)) * SEQ + nn) * HD + d] = f2bf(acc[m][n][r] * scl);
                    }
                }
            }
        }
    } else {
#pragma unroll
        for (int m = 0; m < 4; ++m) {
            int grow = m0 + wm * 64 + m * 16 + lg * 4;
#pragma unroll
            for (int n = 0; n < 4; ++n) {
                int o = o0 + wn * 64 + n * 16 + lr;
                float bias = projb[o];
#pragma unroll
                for (int r = 0; r < 4; ++r)
                    out[(size_t)(grow + r) * CDIM + o] = acc[m][n][r] + bias;
            }
        }
    }
}

// ---------------- fused flash attention: DMA-staged K/V^T with XOR swizzle ----------------
// r18 structure; QK loop UNFENCED (no per-chunk setprio) so the scheduler can interleave
// chunk c+1's MFMAs with chunk c's exp block. PV keeps its pure-MFMA setprio bracket.
__global__ __launch_bounds__(256, 3) void attn_kernel(
    const ushort* __restrict__ qbuf, const ushort* __restrict__ kbuf,
    const ushort* __restrict__ vtbuf, const ushort* __restrict__ biash,
    ushort* __restrict__ attn_out)
{
    __shared__ ushort Ks[2][64 * 64];    // K [kv][hd] bf16, unpadded, swizzled, dbuf
    __shared__ ushort Vt[2][64 * 64];    // V^T [hd][kv] fp16, unpadded, swizzled, dbuf

    const int t = threadIdx.x;
    const int w = t >> 6, l = t & 63;
    const int lr = l & 15, lg = l >> 4;

    const int bid = blockIdx.x;
    const int lid = (bid & 7) * 96 + (bid >> 3);   // XCD-chunked swizzle
    const int h  = lid >> 6;
    const int qt = (lid >> 3) & 7;
    const int b  = lid & 7;

    const int q0 = qt * 128;
    const size_t headoff = (size_t)(b * HEADS + h) * SEQ * HD;
    const int qrb = q0 + w * 32;

    // Q fragments (pre-scaled by 0.125*log2e)
    bfrag aQ[2][2];
#pragma unroll
    for (int n = 0; n < 2; ++n) {
        const ushort* Qp = qbuf + headoff + (size_t)(qrb + n * 16 + lr) * HD;
        aQ[n][0] = *(const bfrag*)(Qp + lg * 8);
        aQ[n][1] = *(const bfrag*)(Qp + 32 + lg * 8);
    }

    float mrun[2] = {-1e30f, -1e30f};
    float lrun[2] = {0.0f, 0.0f};        // PER-LANE partial; reduced in epilogue
    facc Ov[2][4] = {};

    const ushort* bprow[2];
#pragma unroll
    for (int n = 0; n < 2; ++n)
        bprow[n] = biash + ((size_t)h * SEQ + qrb + n * 16 + lr) * SEQ;

    const ushort* kbh  = kbuf  + headoff;                         // [kv][64] bf16
    const ushort* vtbh = vtbuf + (size_t)(b * HEADS + h) * 65536; // [d][1024] fp16
    const int srow = (w << 3) + (l >> 3);
    const int sgr  = ((l & 7) ^ (srow & 7)) << 3;                 // src granule offset (ushorts)

    const int g0 = (lg ^ (lr & 7)) << 3;                          // K granule for kf0

    // ---- prologue: DMA tile0 ----
    GLOAD16(kbh + (size_t)srow * 64 + sgr,            &Ks[0][w * 512]);
    GLOAD16(kbh + (size_t)(srow + 32) * 64 + sgr,     &Ks[0][2048 + w * 512]);
    GLOAD16(vtbh + (size_t)srow * 1024 + sgr,         &Vt[0][w * 512]);
    GLOAD16(vtbh + (size_t)(srow + 32) * 1024 + sgr,  &Vt[0][2048 + w * 512]);
    uint2 bcur[2][4];
#pragma unroll
    for (int n = 0; n < 2; ++n)
#pragma unroll
        for (int c = 0; c < 4; ++c)
            bcur[n][c] = *(const uint2*)(bprow[n] + c * 16 + lg * 4);
    __syncthreads();

    for (int tt = 0; tt < 16; ++tt) {
        const int cur = tt & 1;
        const ushort* Kc = Ks[cur];
        const ushort* Vc = Vt[cur];

        // (0) issue DMA for tile tt+1 into the other buffer
        if (tt < 15) {
            const int kvn = (tt + 1) << 6;
            GLOAD16(kbh + (size_t)(kvn + srow) * 64 + sgr,           &Ks[cur ^ 1][w * 512]);
            GLOAD16(kbh + (size_t)(kvn + srow + 32) * 64 + sgr,      &Ks[cur ^ 1][2048 + w * 512]);
            GLOAD16(vtbh + (size_t)srow * 1024 + kvn + sgr,          &Vt[cur ^ 1][w * 512]);
            GLOAD16(vtbh + (size_t)(srow + 32) * 1024 + kvn + sgr,   &Vt[cur ^ 1][2048 + w * 512]);
        }

        // (1) QK^T (C-init = fp16 bias, pre-scaled) fused with stale-max raw exp2.
        // UNFENCED: no setprio here — scheduler may pipeline MFMA(c+1) under exp(c).
        facc St[2][4];
        h4 pf[2][4];
        float psum[2] = {0.0f, 0.0f};
        float pmax[2] = {-3.0e38f, -3.0e38f};
#pragma unroll
        for (int c = 0; c < 4; ++c) {
            bfrag kf0 = *(const bfrag*)&Kc[(c * 16 + lr) * 64 + g0];
            bfrag kf1 = *(const bfrag*)&Kc[(c * 16 + lr) * 64 + (g0 ^ 32)];
#pragma unroll
            for (int n = 0; n < 2; ++n) {
                uint2 bb = bcur[n][c];
                facc s;
                s[0] = h2f(bb.x & 0xffffu);
                s[1] = h2f(bb.x >> 16);
                s[2] = h2f(bb.y & 0xffffu);
                s[3] = h2f(bb.y >> 16);
                s = __builtin_amdgcn_mfma_f32_16x16x32_bf16(kf0, aQ[n][0], s, 0, 0, 0);
                s = __builtin_amdgcn_mfma_f32_16x16x32_bf16(kf1, aQ[n][1], s, 0, 0, 0);
                St[n][c] = s;
                float p0 = exp2_raw(s[0] - mrun[n]);
                float p1 = exp2_raw(s[1] - mrun[n]);
                float p2f = exp2_raw(s[2] - mrun[n]);
                float p3 = exp2_raw(s[3] - mrun[n]);
                psum[n] += (p0 + p1) + (p2f + p3);
                pmax[n] = fmaxf(pmax[n], fmaxf(fmaxf(s[0], s[1]), fmaxf(s[2], s[3])));
                pf[n][c] = pack4h(p0, p1, p2f, p3);
            }
        }

        // bias prefetch for tile tt+1 (bcur dead after C-init above)
        if (tt < 15) {
            const int kvn = (tt + 1) << 6;
#pragma unroll
            for (int n = 0; n < 2; ++n)
#pragma unroll
                for (int c = 0; c < 4; ++c)
                    bcur[n][c] = *(const uint2*)(bprow[n] + kvn + c * 16 + lg * 4);
        }

        // defer-max check: per-lane LOCAL (shallow dep chain); __any makes it wave-uniform.
        int viol = (pmax[0] > mrun[0] + 14.0f) || (pmax[1] > mrun[1] + 14.0f);
        if (__any(viol)) {
#pragma unroll
            for (int n = 0; n < 2; ++n) {
                float pm = pmax[n];
                pm = fmaxf(pm, __shfl_xor(pm, 16));
                pm = fmaxf(pm, __shfl_xor(pm, 32));
                float mnew = fmaxf(mrun[n], pm);
                float al = exp2_raw(mrun[n] - mnew);
                psum[n] = 0.0f;
#pragma unroll
                for (int c = 0; c < 4; ++c) {
                    float p0 = exp2_raw(St[n][c][0] - mnew);
                    float p1 = exp2_raw(St[n][c][1] - mnew);
                    float p2f = exp2_raw(St[n][c][2] - mnew);
                    float p3 = exp2_raw(St[n][c][3] - mnew);
                    psum[n] += (p0 + p1) + (p2f + p3);
                    pf[n][c] = pack4h(p0, p1, p2f, p3);
                }
#pragma unroll
                for (int r = 0; r < 4; ++r) {
                    float a = __shfl(al, lg * 4 + r);
#pragma unroll
                    for (int d = 0; d < 4; ++d) Ov[n][d][r] *= a;
                }
                lrun[n] *= al;
                mrun[n] = mnew;
            }
        }

        // (4) PV: c outer (8 distinct accumulators). V^T swizzled 8B reads.
        // Pure-MFMA cluster — keep the T5 setprio bracket here.
        __builtin_amdgcn_s_setprio(1);
#pragma unroll
        for (int c = 0; c < 4; ++c) {
#pragma unroll
            for (int d0 = 0; d0 < 4; ++d0) {
                int row = d0 * 16 + lr;
                h4 bv = *(const h4*)&Vc[row * 64 + ((((c * 2 + (lg >> 1)) ^ (lr & 7)) << 3) + ((lg & 1) << 2))];
#pragma unroll
                for (int n = 0; n < 2; ++n)
                    Ov[n][d0] = __builtin_amdgcn_mfma_f32_16x16x16f16(pf[n][c], bv, Ov[n][d0], 0, 0, 0);
            }
        }
        __builtin_amdgcn_s_setprio(0);

        lrun[0] += psum[0];
        lrun[1] += psum[1];

        // (5) single barrier per tile (implicit vmcnt(0) drains the tt+1 DMA)
        if (tt < 15) __syncthreads();
    }

    // epilogue: reduce lrun partials (once), normalize, write
#pragma unroll
    for (int n = 0; n < 2; ++n) {
        float lt = lrun[n];
        lt += __shfl_xor(lt, 16);
        lt += __shfl_xor(lt, 32);
        ushort* op = attn_out + ((size_t)b * SEQ + qrb + n * 16) * CDIM + h * HD;
#pragma unroll
        for (int r = 0; r < 4; ++r) {
            float ll = __shfl(lt, lg * 4 + r);
            float rl = 1.0f / ll;
#pragma unroll
            for (int d = 0; d < 4; ++d)
                op[(size_t)(lg * 4 + r) * CDIM + d * 16 + lr] = f2bf(Ov[n][d][r] * rl);
        }
    }
}

// ---------------- launch ----------------
extern "C" void kernel_launch(void* const* d_in, const int* in_sizes, int n_in,
                              void* d_out, int out_size, void* d_ws, size_t ws_size,
                              hipStream_t stream) {
    const float* x     = (const float*)d_in[0];   // (8,1024,768)
    const float* rel   = (const float*)d_in[1];   // (12,1024,1024)
    const float* qkvw  = (const float*)d_in[2];   // (2304,768)
    const float* projw = (const float*)d_in[3];   // (768,768)
    const float* projb = (const float*)d_in[4];   // (768,)
    float* out = (float*)d_out;

    // Workspace (80,216,064 B). attnb aliases xbf (xbf dead after gemm<0>).
    char* ws = (char*)d_ws;
    ushort* biash = (ushort*)(ws);                 // 12,582,912 halves (fp16, *log2e)
    ushort* qb    = (ushort*)(ws + 25165824);      // bf16 [bh][n][d]
    ushort* kb    = (ushort*)(ws + 37748736);      // bf16 [bh][n][d]
    ushort* vb    = (ushort*)(ws + 50331648);      // fp16 TRANSPOSED [bh][d][n]
    ushort* attnb = (ushort*)(ws + 62914560);      // bf16 (aliases xbf)
    ushort* xbf   = attnb;
    ushort* wbf   = (ushort*)(ws + 75497472);
    ushort* pwbf  = (ushort*)(ws + 79036416);

    cvt_all<<<8448, 256, 0, stream>>>(x, qkvw, projw, xbf, wbf, pwbf);

    // gemm0: y<4 = 256 long-running bias-convert blocks (dispatched first, overlap gemm compute)
    gemm_nt<0><<<dim3(64, 22), 256, 0, stream>>>(xbf, wbf, qb, kb, vb, nullptr, nullptr, rel, biash);
    attn_kernel<<<768, 256, 0, stream>>>(qb, kb, vb, biash, attnb);
    gemm_nt<1><<<dim3(64, 6), 256, 0, stream>>>(attnb, pwbf, nullptr, nullptr, nullptr, projb, out, nullptr, nullptr);
}